// Round 4
// baseline (571.812 us; speedup 1.0000x reference)
//
#include <hip/hip_runtime.h>
#include <cstdint>

#define N_NODES 50000
#define B_SZ 4
#define C_IN 32
#define C_OUT 64
#define K_CHEB 6
#define M_POOL 12500
#define NS32 ((size_t)N_NODES * C_IN)
#define ZS ((size_t)N_NODES * C_OUT)

typedef __bf16 bf16x8 __attribute__((ext_vector_type(8)));
typedef float f32x4 __attribute__((ext_vector_type(4)));
typedef unsigned short ushort_t;

__device__ __forceinline__ unsigned short f2bf(float f) {
    union { float f; unsigned int u; } v;
    v.f = f;
    unsigned int r = v.u + 0x7fffu + ((v.u >> 16) & 1u);
    return (unsigned short)(r >> 16);
}

__device__ __forceinline__ float bf2f(unsigned short u) {
    union { unsigned int u; float f; } v;
    v.u = ((unsigned int)u) << 16;
    return v.f;
}

// ---------------- CSR build ----------------
__global__ void deg_kernel(const int* __restrict__ row, int* __restrict__ deg, int E) {
    int e = blockIdx.x * blockDim.x + threadIdx.x;
    if (e < E) atomicAdd(&deg[row[e]], 1);
}

__global__ void dis_kernel(const int* __restrict__ deg, float* __restrict__ dis, int N) {
    int i = blockIdx.x * blockDim.x + threadIdx.x;
    if (i < N) {
        int d = deg[i];
        dis[i] = d > 0 ? rsqrtf((float)d) : 0.f;
    }
}

__global__ void block_sum_kernel(const int* __restrict__ deg, int* __restrict__ bsum, int N) {
    __shared__ int sm[256];
    int i = blockIdx.x * 256 + threadIdx.x;
    sm[threadIdx.x] = (i < N) ? deg[i] : 0;
    __syncthreads();
    for (int s = 128; s > 0; s >>= 1) {
        if (threadIdx.x < s) sm[threadIdx.x] += sm[threadIdx.x + s];
        __syncthreads();
    }
    if (threadIdx.x == 0) bsum[blockIdx.x] = sm[0];
}

__global__ void scan_bsum_kernel(int* bsum, int nb, int* rowptr, int N, int E) {
    if (blockIdx.x == 0 && threadIdx.x == 0) {
        int run = 0;
        for (int i = 0; i < nb; i++) { int v = bsum[i]; bsum[i] = run; run += v; }
        rowptr[N] = E;
    }
}

__global__ void rowptr_kernel(const int* __restrict__ deg, const int* __restrict__ bsum,
                              int* __restrict__ rowptr, int N) {
    __shared__ int sm[256];
    int i = blockIdx.x * 256 + threadIdx.x;
    sm[threadIdx.x] = (i < N) ? deg[i] : 0;
    __syncthreads();
    if (threadIdx.x == 0) {
        int run = bsum[blockIdx.x];
        for (int t = 0; t < 256; t++) { int v = sm[t]; sm[t] = run; run += v; }
    }
    __syncthreads();
    if (i < N) rowptr[i] = sm[threadIdx.x];
}

__global__ void place_kernel(const int* __restrict__ row, const int* __restrict__ col,
                             const float* __restrict__ dis, const int* __restrict__ rowptr,
                             int* __restrict__ cursor, int* __restrict__ col_s,
                             float* __restrict__ norm_s, int E) {
    int e = blockIdx.x * blockDim.x + threadIdx.x;
    if (e < E) {
        int r = row[e], c = col[e];
        int pos = rowptr[r] + atomicAdd(&cursor[r], 1);
        col_s[pos] = c;
        norm_s[pos] = -dis[r] * dis[c];
    }
}

__global__ void place2_kernel(const int* __restrict__ prow, const int* __restrict__ pcol,
                              const float* __restrict__ pval, const int* __restrict__ rowptr,
                              int* __restrict__ cursor, int* __restrict__ col_s,
                              float* __restrict__ val_s, int P) {
    int e = blockIdx.x * blockDim.x + threadIdx.x;
    if (e < P) {
        int r = prow[e];
        int pos = rowptr[r] + atomicAdd(&cursor[r], 1);
        col_s[pos] = pcol[e];
        val_s[pos] = pval[e];
    }
}

// ---------------- fp32 -> bf16 cast (2 elements/thread) ----------------
__global__ void cast_bf_kernel(const float* __restrict__ in, unsigned int* __restrict__ out,
                               int n2) {
    int i = blockIdx.x * 256 + threadIdx.x;
    if (i < n2) {
        float a = in[2 * i], b = in[2 * i + 1];
        out[i] = (unsigned int)f2bf(a) | ((unsigned int)f2bf(b) << 16);
    }
}

// ---------------- Chebyshev propagation: bf16 in/out, one batch per block ----------------
// batch chosen by XCD so each XCD pair gathers only its 3.2 MB slice (L2-resident)
__global__ void prop_kernel(const ushort_t* __restrict__ hbf, const ushort_t* __restrict__ p2bf,
                            ushort_t* __restrict__ outbf,
                            const int* __restrict__ rowptr, const int* __restrict__ col_s,
                            const float* __restrict__ norm_s, float alpha) {
    int bid = blockIdx.x;
    int xcd = bid & 7;
    int b = xcd >> 1;
    int rowblk = ((bid >> 3) << 1) | (xcd & 1);  // [0, 6250)
    int r = rowblk * 8 + (threadIdx.x >> 5);
    int c = threadIdx.x & 31;
    if (r >= N_NODES) return;
    const ushort_t* hb = hbf + (size_t)b * NS32;
    float acc = 0.f;
    int p0 = rowptr[r], p1 = rowptr[r + 1];
    int p = p0;
    for (; p + 3 < p1; p += 4) {
        int cl0 = col_s[p], cl1 = col_s[p + 1], cl2 = col_s[p + 2], cl3 = col_s[p + 3];
        float n0 = norm_s[p], n1 = norm_s[p + 1], n2 = norm_s[p + 2], n3 = norm_s[p + 3];
        float v0 = bf2f(hb[(size_t)cl0 * C_IN + c]);
        float v1 = bf2f(hb[(size_t)cl1 * C_IN + c]);
        float v2 = bf2f(hb[(size_t)cl2 * C_IN + c]);
        float v3 = bf2f(hb[(size_t)cl3 * C_IN + c]);
        acc += v0 * n0 + v1 * n1 + v2 * n2 + v3 * n3;
    }
    for (; p < p1; ++p) {
        acc += bf2f(hb[(size_t)col_s[p] * C_IN + c]) * norm_s[p];
    }
    size_t idx = (size_t)b * NS32 + (size_t)r * C_IN + c;
    float v = alpha * acc;
    if (p2bf) v -= bf2f(p2bf[idx]);
    outbf[idx] = f2bf(v);
}

// ---------------- W pack: [s][t][lane][j] bf16 fragment order ----------------
__global__ void packW_kernel(const float* __restrict__ W, ushort_t* __restrict__ Wp) {
    int i = blockIdx.x * 256 + threadIdx.x;
    if (i >= K_CHEB * 4 * 64 * 8) return;
    int j = i & 7;
    int lane = (i >> 3) & 63;
    int t = (i >> 9) & 3;
    int s = i >> 11;
    int k = (lane >> 4) * 8 + j;
    int col = t * 16 + (lane & 15);
    Wp[i] = f2bf(W[((size_t)s * C_IN + k) * C_OUT + col]);
}

// ---------------- Fused 3-source MFMA GEMM (A direct from bf16 buffers) ----------------
__global__ void gemm_mfma_kernel(const ushort_t* __restrict__ T0, const ushort_t* __restrict__ T1,
                                 const ushort_t* __restrict__ T2,
                                 const ushort_t* __restrict__ Wp,
                                 const float* __restrict__ bias, float* __restrict__ z,
                                 int second) {
    int lane = threadIdx.x & 63;
    int wave = (blockIdx.x << 2) + (threadIdx.x >> 6);
    int r0 = wave << 4;  // 16 rows/wave; 200000/16 = 12500 waves
    int ga = r0 + (lane & 15);
    int koff = (lane >> 4) * 8;
    const ushort_t* Ts[3] = {T0, T1, T2};

    bf16x8 afr[3];
#pragma unroll
    for (int s = 0; s < 3; s++)
        afr[s] = *(const bf16x8*)(Ts[s] + (size_t)ga * C_IN + koff);

    int orow = r0 + ((lane >> 4) << 2);
#pragma unroll
    for (int t = 0; t < 4; t++) {
        f32x4 acc = {0.f, 0.f, 0.f, 0.f};
#pragma unroll
        for (int s = 0; s < 3; s++) {
            bf16x8 bfr = *(const bf16x8*)(Wp + (((s << 2) + t) * 64 + lane) * 8);
            acc = __builtin_amdgcn_mfma_f32_16x16x32_bf16(afr[s], bfr, acc, 0, 0, 0);
        }
        int col = (t << 4) + (lane & 15);
        float bv = bias[col];
#pragma unroll
        for (int rg = 0; rg < 4; rg++) {
            size_t idx = (size_t)(orow + rg) * C_OUT + col;
            float v = acc[rg];
            if (!second) {
                z[idx] = v + bv;
            } else {
                v += z[idx];
                z[idx] = v > 0.f ? v : (expf(v) - 1.f);
            }
        }
    }
}

// ---------------- Pool: deterministic CSR gather-reduce ----------------
__global__ void pool_csr_kernel(const float* __restrict__ z, const int* __restrict__ rowptr,
                                const int* __restrict__ col_s, const float* __restrict__ val_s,
                                float* __restrict__ out) {
    int r = blockIdx.x * 4 + (threadIdx.x >> 6);
    int c = threadIdx.x & 63;
    if (r >= M_POOL) return;
    float a0 = 0.f, a1 = 0.f, a2 = 0.f, a3 = 0.f;
    int p0 = rowptr[r], p1 = rowptr[r + 1];
    for (int p = p0; p < p1; ++p) {
        int cl = col_s[p];
        float v = val_s[p];
        const float* zb = z + (size_t)cl * C_OUT + c;
        a0 += zb[0] * v;
        a1 += zb[ZS] * v;
        a2 += zb[2 * ZS] * v;
        a3 += zb[3 * ZS] * v;
    }
    size_t idx = (size_t)r * C_OUT + c;
    out[idx]                           = a0;
    out[idx + (size_t)M_POOL * 64]     = a1;
    out[idx + 2 * (size_t)M_POOL * 64] = a2;
    out[idx + 3 * (size_t)M_POOL * 64] = a3;
}

extern "C" void kernel_launch(void* const* d_in, const int* in_sizes, int n_in,
                              void* d_out, int out_size, void* d_ws, size_t ws_size,
                              hipStream_t stream) {
    const float* x    = (const float*)d_in[0];
    const int*   ei   = (const int*)d_in[1];
    const int*   prow = (const int*)d_in[2];
    const int*   pcol = (const int*)d_in[3];
    const float* pval = (const float*)d_in[4];
    const float* W    = (const float*)d_in[5];
    const float* bias = (const float*)d_in[6];
    const int E = in_sizes[1] / 2;
    const int P = in_sizes[2];
    const int N = N_NODES;
    const int* row = ei;
    const int* col = ei + E;

    char* ws = (char*)d_ws;
    size_t o = 0;
    auto alloc = [&](size_t bytes) -> char* {
        char* p = ws + o;
        o += (bytes + 255) & ~(size_t)255;
        return p;
    };
    int nb  = (N + 255) / 256;
    int nb2 = (M_POOL + 255) / 256;
    int*   deg     = (int*)alloc((size_t)N * 4);
    float* dis     = (float*)alloc((size_t)N * 4);
    int*   rowptr  = (int*)alloc((size_t)(N + 1) * 4);
    int*   cursor  = (int*)alloc((size_t)N * 4);
    int*   bsum    = (int*)alloc((size_t)nb * 4);
    int*   col_s   = (int*)alloc((size_t)E * 4);
    float* norm_s  = (float*)alloc((size_t)E * 4);
    int*   deg2    = (int*)alloc((size_t)M_POOL * 4);
    int*   rowptr2 = (int*)alloc((size_t)(M_POOL + 1) * 4);
    int*   cursor2 = (int*)alloc((size_t)M_POOL * 4);
    int*   pcol_s  = (int*)alloc((size_t)P * 4);
    float* pval_s  = (float*)alloc((size_t)P * 4);
    ushort_t* Wp   = (ushort_t*)alloc((size_t)K_CHEB * 4 * 64 * 8 * 2);
    ushort_t* xbf  = (ushort_t*)alloc((size_t)B_SZ * NS32 * 2);
    ushort_t* bfA  = (ushort_t*)alloc((size_t)B_SZ * NS32 * 2);
    ushort_t* bfB  = (ushort_t*)alloc((size_t)B_SZ * NS32 * 2);
    ushort_t* bfC  = (ushort_t*)alloc((size_t)B_SZ * NS32 * 2);
    float*    z    = (float*)alloc((size_t)B_SZ * N * C_OUT * 4);

    hipMemsetAsync(deg, 0, (size_t)N * 4, stream);
    hipMemsetAsync(cursor, 0, (size_t)N * 4, stream);
    hipMemsetAsync(deg2, 0, (size_t)M_POOL * 4, stream);
    hipMemsetAsync(cursor2, 0, (size_t)M_POOL * 4, stream);

    // main CSR
    deg_kernel<<<(E + 255) / 256, 256, 0, stream>>>(row, deg, E);
    dis_kernel<<<(N + 255) / 256, 256, 0, stream>>>(deg, dis, N);
    block_sum_kernel<<<nb, 256, 0, stream>>>(deg, bsum, N);
    scan_bsum_kernel<<<1, 64, 0, stream>>>(bsum, nb, rowptr, N, E);
    rowptr_kernel<<<nb, 256, 0, stream>>>(deg, bsum, rowptr, N);
    place_kernel<<<(E + 255) / 256, 256, 0, stream>>>(row, col, dis, rowptr, cursor,
                                                      col_s, norm_s, E);
    // pool CSR
    deg_kernel<<<(P + 255) / 256, 256, 0, stream>>>(prow, deg2, P);
    block_sum_kernel<<<nb2, 256, 0, stream>>>(deg2, bsum, M_POOL);
    scan_bsum_kernel<<<1, 64, 0, stream>>>(bsum, nb2, rowptr2, M_POOL, P);
    rowptr_kernel<<<nb2, 256, 0, stream>>>(deg2, bsum, rowptr2, M_POOL);
    place2_kernel<<<(P + 255) / 256, 256, 0, stream>>>(prow, pcol, pval, rowptr2, cursor2,
                                                       pcol_s, pval_s, P);
    // W pack + x cast
    packW_kernel<<<(K_CHEB * 4 * 64 * 8 + 255) / 256, 256, 0, stream>>>(W, Wp);
    int n2 = (int)(B_SZ * NS32 / 2);
    cast_bf_kernel<<<(n2 + 255) / 256, 256, 0, stream>>>(x, (unsigned int*)xbf, n2);

    int prop_blocks = (N / 8) * B_SZ;  // 25000, divisible by 8
    int gemm_blocks = (B_SZ * N) / 64; // 3125

    // T1 = prop(x); T2 = 2*prop(T1) - x
    prop_kernel<<<prop_blocks, 256, 0, stream>>>(xbf, nullptr, bfA, rowptr, col_s, norm_s, 1.0f);
    prop_kernel<<<prop_blocks, 256, 0, stream>>>(bfA, xbf, bfB, rowptr, col_s, norm_s, 2.0f);
    // z = [x,T1,T2] @ W[0:3] + bias
    gemm_mfma_kernel<<<gemm_blocks, 256, 0, stream>>>(xbf, bfA, bfB, Wp, bias, z, 0);
    // T3 = 2*prop(T2)-T1; T4 = 2*prop(T3)-T2; T5 = 2*prop(T4)-T3
    prop_kernel<<<prop_blocks, 256, 0, stream>>>(bfB, bfA, bfC, rowptr, col_s, norm_s, 2.0f);
    prop_kernel<<<prop_blocks, 256, 0, stream>>>(bfC, bfB, bfA, rowptr, col_s, norm_s, 2.0f);
    prop_kernel<<<prop_blocks, 256, 0, stream>>>(bfA, bfC, bfB, rowptr, col_s, norm_s, 2.0f);
    // z = ELU(z + [T3,T4,T5] @ W[3:6])
    gemm_mfma_kernel<<<gemm_blocks, 256, 0, stream>>>(bfC, bfA, bfB, Wp + 3 * 4 * 64 * 8,
                                                      bias, z, 1);
    // pool
    pool_csr_kernel<<<(M_POOL + 3) / 4, 256, 0, stream>>>(z, rowptr2, pcol_s, pval_s,
                                                          (float*)d_out);
}